// Round 1
// baseline (127.756 us; speedup 1.0000x reference)
//
#include <hip/hip_runtime.h>
#include <hip/hip_bf16.h>
#include <math.h>

#define BB 8
#define HH 256
#define WW 256
#define EPS 1e-6
#define INFV 1e10f

// Workspace layout:
//  acc (double[25]): [0..7]=sum(pred*t) per batch, [8..15]=sum(pred^2),
//                    [16..23]=sum(t^2), [24]=sum(pred*dist) global
//  g1 (float[B*H*W]) at byte offset 256: row-pass squared dist to nearest t==1 (along W)
//  g0 (float[B*H*W]) after g1: row-pass squared dist to nearest t==0

__global__ __launch_bounds__(256) void k_rowpass(
    const float* __restrict__ pred, const float* __restrict__ target,
    const int* __restrict__ from_logits,
    float* __restrict__ g1, float* __restrict__ g0, double* __restrict__ acc)
{
    const int row = blockIdx.x;        // 0..B*H-1
    const int b   = row >> 8;
    const int c   = threadIdx.x;       // column 0..255
    const int base = row * WW;

    __shared__ float trow[WW];
    const float t = target[base + c];
    const float p = pred[base + c];
    const int fl = *from_logits;
    const float sp = fl ? (1.0f / (1.0f + __expf(-p))) : p;
    trow[c] = t;
    __syncthreads();

    // outward scan along the row for nearest 1 and nearest 0
    const bool isone = (t > 0.5f);
    float best1 = isone ? 0.0f : INFV;
    float best0 = isone ? INFV : 0.0f;
    for (int d = 1; d < WW; ++d) {
        const float dd = (float)(d * d);
        if (dd >= best0 && dd >= best1) break;
        const int l = c - d, r = c + d;
        if (l >= 0) {
            if (trow[l] > 0.5f) best1 = fminf(best1, dd);
            else                best0 = fminf(best0, dd);
        }
        if (r < WW) {
            if (trow[r] > 0.5f) best1 = fminf(best1, dd);
            else                best0 = fminf(best0, dd);
        }
    }
    g1[base + c] = best1;
    g0[base + c] = best0;

    // dice partial sums for this row
    float s_pt = sp * t;
    float s_p2 = sp * sp;
    float s_t  = t * t;
    #pragma unroll
    for (int o = 32; o > 0; o >>= 1) {
        s_pt += __shfl_down(s_pt, o);
        s_p2 += __shfl_down(s_p2, o);
        s_t  += __shfl_down(s_t,  o);
    }
    __shared__ float red[12];
    const int lane = c & 63, wid = c >> 6;
    if (lane == 0) { red[wid] = s_pt; red[4 + wid] = s_p2; red[8 + wid] = s_t; }
    __syncthreads();
    if (c == 0) {
        const float pt = red[0] + red[1] + red[2] + red[3];
        const float p2 = red[4] + red[5] + red[6] + red[7];
        const float st = red[8] + red[9] + red[10] + red[11];
        atomicAdd(&acc[b],      (double)pt);
        atomicAdd(&acc[8 + b],  (double)p2);
        atomicAdd(&acc[16 + b], (double)st);
    }
}

__global__ __launch_bounds__(256) void k_colpass(
    const float* __restrict__ pred, const int* __restrict__ from_logits,
    const float* __restrict__ g1, const float* __restrict__ g0,
    double* __restrict__ acc)
{
    const int blk = blockIdx.x;       // 0..B*W-1
    const int b   = blk >> 8;
    const int c   = blk & 255;        // column
    const int r   = threadIdx.x;      // row 0..255

    __shared__ float c1[HH], c0[HH];
    const int idx = (b * HH + r) * WW + c;
    c1[r] = g1[idx];
    c0[r] = g0[idx];
    const float p = pred[idx];
    const int fl = *from_logits;
    const float sp = fl ? (1.0f / (1.0f + __expf(-p))) : p;
    __syncthreads();

    float best1 = c1[r];
    float best0 = c0[r];
    for (int d = 1; d < HH; ++d) {
        const float dd = (float)(d * d);
        if (dd >= best0 && dd >= best1) break;
        const int u = r - d, v = r + d;
        if (u >= 0) {
            best1 = fminf(best1, c1[u] + dd);
            best0 = fminf(best0, c0[u] + dd);
        }
        if (v < HH) {
            best1 = fminf(best1, c1[v] + dd);
            best0 = fminf(best0, c0[v] + dd);
        }
    }
    const float dist = sqrtf(best1) + sqrtf(best0);
    float s_pd = sp * dist;

    #pragma unroll
    for (int o = 32; o > 0; o >>= 1) s_pd += __shfl_down(s_pd, o);
    __shared__ float red[4];
    const int lane = r & 63, wid = r >> 6;
    if (lane == 0) red[wid] = s_pd;
    __syncthreads();
    if (r == 0) {
        const float pd = red[0] + red[1] + red[2] + red[3];
        atomicAdd(&acc[24], (double)pd);
    }
}

__global__ void k_final(const double* __restrict__ acc, float* __restrict__ out)
{
    if (threadIdx.x == 0 && blockIdx.x == 0) {
        double dsum = 0.0;
        for (int b = 0; b < BB; ++b) {
            const double pt = acc[b];
            const double p2 = acc[8 + b];
            const double st = acc[16 + b];
            dsum += 1.0 - (2.0 * pt + EPS) / (p2 + st + EPS);
        }
        const double d_loss = dsum / (double)BB;
        const double b_loss = acc[24] / (double)(BB * HH * WW);
        out[0] = (float)(d_loss + b_loss);   // ALPHA = BETA = 1
    }
}

extern "C" void kernel_launch(void* const* d_in, const int* in_sizes, int n_in,
                              void* d_out, int out_size, void* d_ws, size_t ws_size,
                              hipStream_t stream) {
    const float* pred   = (const float*)d_in[0];
    const float* target = (const float*)d_in[1];
    const int*   fl     = (const int*)d_in[2];
    float* out = (float*)d_out;

    double* acc = (double*)d_ws;
    float*  g1  = (float*)((char*)d_ws + 256);
    float*  g0  = g1 + BB * HH * WW;

    hipMemsetAsync(d_ws, 0, 256, stream);
    k_rowpass<<<BB * HH, 256, 0, stream>>>(pred, target, fl, g1, g0, acc);
    k_colpass<<<BB * WW, 256, 0, stream>>>(pred, fl, g1, g0, acc);
    k_final<<<1, 64, 0, stream>>>(acc, out);
}

// Round 2
// 74.397 us; speedup vs baseline: 1.7172x; 1.7172x over previous
//
#include <hip/hip_runtime.h>
#include <math.h>

#define BB 8
#define HH 256
#define WW 256
#define NROW (BB*HH)   // 2048 row-pass blocks
#define NCOL (BB*WW)   // 2048 col-pass blocks
#define EPSF 1e-6f
#define INFV 1e10f

// Workspace layout (floats):
//  [0      .. 2047]  part_pt  (per-row  sum sp*t)
//  [2048   .. 4095]  part_p2  (per-row  sum sp^2)
//  [4096   .. 6143]  part_st  (per-row  sum t^2)
//  [6144   .. 8191]  part_pd  (per-col-block sum sp*dist)
//  then (32KB offset) uint2 gsp[B*W*H]: transposed packed
//      .x = g1(u16, low) | g0(u16, high)   row-pass squared distances
//      .y = sigmoid(pred) bits (f32)
// All entries fully overwritten before read -> no memset needed, no atomics.

__global__ __launch_bounds__(256) void k_rowpass(
    const float* __restrict__ pred, const float* __restrict__ target,
    const int* __restrict__ from_logits,
    uint2* __restrict__ gsp, float* __restrict__ part)
{
    const int row = blockIdx.x;        // b*H + r
    const int b   = row >> 8;
    const int r   = row & 255;
    const int c   = threadIdx.x;       // column 0..255
    const int base = row * WW;

    __shared__ float trow[WW];
    const float t = target[base + c];
    const float p = pred[base + c];
    const float sp = (*from_logits) ? (1.0f / (1.0f + __expf(-p))) : p;
    trow[c] = t;
    __syncthreads();

    // outward scan along the row: exact 1D min-plus with early exit
    const bool isone = (t > 0.5f);
    float best1 = isone ? 0.0f : INFV;
    float best0 = isone ? INFV : 0.0f;
    for (int d = 1; d < WW; ++d) {
        const float dd = (float)(d * d);
        if (dd >= best0 && dd >= best1) break;
        const int l = c - d, rr = c + d;
        if (l >= 0) {
            if (trow[l] > 0.5f) best1 = fminf(best1, dd);
            else                best0 = fminf(best0, dd);
        }
        if (rr < WW) {
            if (trow[rr] > 0.5f) best1 = fminf(best1, dd);
            else                best0 = fminf(best0, dd);
        }
    }
    // pack (values are exact integers <= 65025, or INFV -> 0xFFFF sentinel)
    const unsigned u1 = (best1 > 65500.0f) ? 0xFFFFu : (unsigned)best1;
    const unsigned u0 = (best0 > 65500.0f) ? 0xFFFFu : (unsigned)best0;
    uint2 rec;
    rec.x = u1 | (u0 << 16);
    rec.y = __float_as_uint(sp);
    gsp[(b * WW + c) * HH + r] = rec;   // transposed scatter write (no stall)

    // dice partial sums for this row -> per-row slots, no atomics
    float s_pt = sp * t;
    float s_p2 = sp * sp;
    float s_t  = t * t;
    #pragma unroll
    for (int o = 32; o > 0; o >>= 1) {
        s_pt += __shfl_down(s_pt, o);
        s_p2 += __shfl_down(s_p2, o);
        s_t  += __shfl_down(s_t,  o);
    }
    __shared__ float red[12];
    const int lane = c & 63, wid = c >> 6;
    if (lane == 0) { red[wid] = s_pt; red[4 + wid] = s_p2; red[8 + wid] = s_t; }
    __syncthreads();
    if (c == 0) {
        part[row]            = red[0] + red[1] + red[2] + red[3];
        part[NROW + row]     = red[4] + red[5] + red[6] + red[7];
        part[2 * NROW + row] = red[8] + red[9] + red[10] + red[11];
    }
}

__global__ __launch_bounds__(256) void k_colpass(
    const uint2* __restrict__ gsp, float* __restrict__ part_pd)
{
    const int blk = blockIdx.x;       // b*W + c
    const int r   = threadIdx.x;      // row 0..255

    __shared__ float c1[HH], c0[HH];
    const uint2 rec = gsp[blk * HH + r];   // fully coalesced
    const unsigned u1 = rec.x & 0xFFFFu, u0 = rec.x >> 16;
    const float f1 = (u1 == 0xFFFFu) ? INFV : (float)u1;
    const float f0 = (u0 == 0xFFFFu) ? INFV : (float)u0;
    const float sp = __uint_as_float(rec.y);
    c1[r] = f1; c0[r] = f0;
    __syncthreads();

    float best1 = f1;
    float best0 = f0;
    for (int d = 1; d < HH; ++d) {
        const float dd = (float)(d * d);
        if (dd >= best0 && dd >= best1) break;
        const int u = r - d, v = r + d;
        if (u >= 0) {
            best1 = fminf(best1, c1[u] + dd);
            best0 = fminf(best0, c0[u] + dd);
        }
        if (v < HH) {
            best1 = fminf(best1, c1[v] + dd);
            best0 = fminf(best0, c0[v] + dd);
        }
    }
    float s_pd = sp * (sqrtf(best1) + sqrtf(best0));

    #pragma unroll
    for (int o = 32; o > 0; o >>= 1) s_pd += __shfl_down(s_pd, o);
    __shared__ float red[4];
    const int lane = r & 63, wid = r >> 6;
    if (lane == 0) red[wid] = s_pd;
    __syncthreads();
    if (r == 0) part_pd[blk] = red[0] + red[1] + red[2] + red[3];
}

__global__ __launch_bounds__(256) void k_final(
    const float* __restrict__ part, float* __restrict__ out)
{
    const int t = threadIdx.x;

    // boundary: sum part_pd[0..2047]
    float s = 0.0f;
    for (int i = t; i < NCOL; i += 256) s += part[3 * NROW + i];
    #pragma unroll
    for (int o = 32; o > 0; o >>= 1) s += __shfl_down(s, o);
    __shared__ float bsum[4];
    if ((t & 63) == 0) bsum[t >> 6] = s;

    // dice: batch b = t>>5, 32 lanes per batch, 8 rows each
    const int b = t >> 5, j = t & 31;
    float pt = 0.0f, p2 = 0.0f, st = 0.0f;
    for (int k = j; k < HH; k += 32) {
        const int idx = b * HH + k;
        pt += part[idx];
        p2 += part[NROW + idx];
        st += part[2 * NROW + idx];
    }
    #pragma unroll
    for (int o = 16; o > 0; o >>= 1) {
        pt += __shfl_down(pt, o, 32);
        p2 += __shfl_down(p2, o, 32);
        st += __shfl_down(st, o, 32);
    }
    __shared__ float dice[8];
    if (j == 0) dice[b] = 1.0f - (2.0f * pt + EPSF) / (p2 + st + EPSF);
    __syncthreads();

    if (t == 0) {
        float dsum = 0.0f;
        #pragma unroll
        for (int bb = 0; bb < 8; ++bb) dsum += dice[bb];
        const float b_loss = (bsum[0] + bsum[1] + bsum[2] + bsum[3])
                             / (float)(BB * HH * WW);
        out[0] = dsum / (float)BB + b_loss;   // ALPHA = BETA = 1
    }
}

extern "C" void kernel_launch(void* const* d_in, const int* in_sizes, int n_in,
                              void* d_out, int out_size, void* d_ws, size_t ws_size,
                              hipStream_t stream) {
    const float* pred   = (const float*)d_in[0];
    const float* target = (const float*)d_in[1];
    const int*   fl     = (const int*)d_in[2];
    float* out = (float*)d_out;

    float* part = (float*)d_ws;                       // 8192 floats = 32 KB
    uint2* gsp  = (uint2*)((char*)d_ws + 32 * 1024);  // 4 MB packed transposed

    k_rowpass<<<NROW, 256, 0, stream>>>(pred, target, fl, gsp, part);
    k_colpass<<<NCOL, 256, 0, stream>>>(gsp, part + 3 * NROW);
    k_final<<<1, 256, 0, stream>>>(part, out);
}